// Round 5
// baseline (2222.239 us; speedup 1.0000x reference)
//
#include <hip/hip_runtime.h>
#include <math.h>

#define NN 100000
#define EE 3200000
#define NCH 32
#define CAP 96          // padded CSR row capacity; P(deg>=96)~5e-20 per row
#define FILL_PASSES 12

typedef unsigned short ushortT;
typedef unsigned int uintT;

__device__ __forceinline__ ushortT f2b(float f) {
  uintT u = __float_as_uint(f);
  uintT r = u + 0x7fffu + ((u >> 16) & 1u);  // round-to-nearest-even
  return (ushortT)(r >> 16);
}
__device__ __forceinline__ uintT pack2(float x, float y) {
  return (uintT)f2b(x) | ((uintT)f2b(y) << 16);
}

// ---------------- setup kernels ----------------

__global__ void init_cursor_k(int* __restrict__ cur) {
  int i = blockIdx.x * blockDim.x + threadIdx.x;
  if (i < NN) cur[i] = i * CAP;
}

// windowed scatter into padded CSR: rows in [lo,hi) only
__global__ void fill_k(const int* __restrict__ ei, int* __restrict__ cursor,
                       int* __restrict__ colc, int lo, int hi) {
  int t = blockIdx.x * blockDim.x + threadIdx.x;
  if (t * 4 >= EE) return;
  int4 r4 = ((const int4*)ei)[t];
  int4 c4 = ((const int4*)(ei + EE))[t];
  if (r4.x != c4.x && r4.x >= lo && r4.x < hi) colc[atomicAdd(&cursor[r4.x], 1)] = c4.x;
  if (r4.y != c4.y && r4.y >= lo && r4.y < hi) colc[atomicAdd(&cursor[r4.y], 1)] = c4.y;
  if (r4.z != c4.z && r4.z >= lo && r4.z < hi) colc[atomicAdd(&cursor[r4.z], 1)] = c4.z;
  if (r4.w != c4.w && r4.w >= lo && r4.w < hi) colc[atomicAdd(&cursor[r4.w], 1)] = c4.w;
}

// degree = cursor_final - row_base -> dinv
__global__ void dinv_k(const int* __restrict__ rend, float* __restrict__ dinv) {
  int i = blockIdx.x * blockDim.x + threadIdx.x;
  if (i >= NN) return;
  int c = rend[i] - i * CAP;
  dinv[i] = (c > 0) ? rsqrtf((float)c) : 0.f;
}

// zero sentinel rows (row NN) of all gather tables
__global__ void init_sent_k(uintT* Uh, uintT* Ua16, uintT* Ub16, float4* Uxf,
                            float4* Uaf, float4* Ubf) {
  int t = threadIdx.x;
  if (t < 16) {
    Uh[(size_t)NN * 16 + t] = 0u;
    Ua16[(size_t)NN * 16 + t] = 0u;
    Ub16[(size_t)NN * 16 + t] = 0u;
  }
  if (t == 0) {
    float4 z = make_float4(0.f, 0.f, 0.f, 0.f);
    Uxf[NN] = z; Uaf[NN] = z; Ubf[NN] = z;
  }
}

__global__ __launch_bounds__(256) void prescale_x_k(const float* __restrict__ x,
                                                    const float* __restrict__ dinv,
                                                    float4* __restrict__ Ux) {
  int i = blockIdx.x * blockDim.x + threadIdx.x;
  if (i >= NN) return;
  float di = dinv[i];
  Ux[i] = make_float4(di * x[3 * i], di * x[3 * i + 1], di * x[3 * i + 2], 0.f);
}

// ---------------- layer kernels ----------------

// 8 lanes per row, F=3, 4 gathers in flight/lane. Pure sum of prescaled rows.
template <bool FIRST>
__global__ __launch_bounds__(256) void cheb_f3_k(
    const int* __restrict__ rend, const int* __restrict__ colc,
    const float* __restrict__ dinv, const float4* __restrict__ U,
    const float* __restrict__ A, float* __restrict__ C,
    float4* __restrict__ Uo) {
  int t8 = blockIdx.x * blockDim.x + threadIdx.x;
  int i = t8 >> 3, q = t8 & 7;
  if (i >= NN) return;
  int s = i * CAP, e = rend[i];
  float a0 = 0.f, a1 = 0.f, a2 = 0.f;
  for (int t = s + q; t < e; t += 32) {
#pragma unroll
    for (int u = 0; u < 4; ++u) {
      int tt = t + 8 * u;
      int cc = (tt < e) ? colc[tt] : NN;  // sentinel row NN is zero
      float4 r = U[cc];
      a0 += r.x; a1 += r.y; a2 += r.z;
    }
  }
  a0 += __shfl_xor(a0, 1); a1 += __shfl_xor(a1, 1); a2 += __shfl_xor(a2, 1);
  a0 += __shfl_xor(a0, 2); a1 += __shfl_xor(a1, 2); a2 += __shfl_xor(a2, 2);
  a0 += __shfl_xor(a0, 4); a1 += __shfl_xor(a1, 4); a2 += __shfl_xor(a2, 4);
  if (q == 0) {
    float di = dinv[i];
    float v0, v1, v2;
    if (FIRST) {
      v0 = -di * a0; v1 = -di * a1; v2 = -di * a2;
    } else {
      v0 = fmaf(-2.f * di, a0, -A[3 * i + 0]);
      v1 = fmaf(-2.f * di, a1, -A[3 * i + 1]);
      v2 = fmaf(-2.f * di, a2, -A[3 * i + 2]);
    }
    C[3 * i + 0] = v0; C[3 * i + 1] = v1; C[3 * i + 2] = v2;
    Uo[i] = make_float4(di * v0, di * v1, di * v2, 0.f);
  }
}

// Layer-1 batched GEMM over all 24 T-planes + bias + SiLU -> bf16 h + prescaled Uh.
__global__ __launch_bounds__(256) void gemm_l1_k(const float* __restrict__ x,
                                                 const float* __restrict__ Tall,
                                                 const float* __restrict__ W1,
                                                 const float* __restrict__ b1,
                                                 const float* __restrict__ dinv,
                                                 ushortT* __restrict__ h1,
                                                 ushortT* __restrict__ Uh) {
  __shared__ float Wl[24 * 96];
  for (int t = threadIdx.x; t < 24 * 96; t += 256) Wl[t] = W1[t];
  __syncthreads();
  int t = blockIdx.x * blockDim.x + threadIdx.x;
  if (t >= NN * NCH) return;
  int i = t >> 5, j = t & 31;
  float g = b1[j];
  g = fmaf(x[i * 3 + 0], Wl[j],
      fmaf(x[i * 3 + 1], Wl[32 + j], fmaf(x[i * 3 + 2], Wl[64 + j], g)));
#pragma unroll
  for (int k = 1; k < 24; ++k) {
    const float* Tp = Tall + ((size_t)(k - 1) * NN + i) * 3;
    g = fmaf(Tp[0], Wl[k * 96 + j],
        fmaf(Tp[1], Wl[k * 96 + 32 + j], fmaf(Tp[2], Wl[k * 96 + 64 + j], g)));
  }
  float sv = g / (1.f + expf(-g));
  h1[t] = f2b(sv);
  Uh[t] = f2b(dinv[i] * sv);
}

// acc = in(N x 32, bf16) @ W(32 x 32, f32)
__global__ __launch_bounds__(256) void gemm_k0_b16_k(const ushortT* __restrict__ in,
                                                     const float* __restrict__ W,
                                                     float* __restrict__ acc) {
  __shared__ float Wl[NCH * NCH];
  for (int t = threadIdx.x; t < NCH * NCH; t += 256) Wl[t] = W[t];
  __syncthreads();
  int t = blockIdx.x * blockDim.x + threadIdx.x;
  if (t >= NN * NCH) return;
  int i = t >> 5, j = t & 31;
  const uintT* bi = (const uintT*)in + (size_t)i * 16;
  float g = 0.f;
#pragma unroll
  for (int p = 0; p < 16; ++p) {
    uintT u = bi[p];
    g = fmaf(__uint_as_float(u << 16), Wl[(2 * p) * NCH + j], g);
    g = fmaf(__uint_as_float(u & 0xffff0000u), Wl[(2 * p + 1) * NCH + j], g);
  }
  acc[t] = g;
}

// One wave per row; 16 lanes x 4 edge-groups; 8 gathers in flight per lane.
// C = (FIRST ? L : 2L - A) bf16; Uo = dinv*C bf16; acc += C @ Wk.
template <bool FIRST>
__global__ __launch_bounds__(256) void cheb_b16_k(
    const int* __restrict__ rend, const int* __restrict__ colc,
    const float* __restrict__ dinv, const uintT* __restrict__ U,
    const uintT* __restrict__ A, uintT* __restrict__ C,
    uintT* __restrict__ Uo, float* __restrict__ acc,
    const float* __restrict__ Wk) {
  __shared__ float Wl[NCH * NCH];
  for (int t = threadIdx.x; t < NCH * NCH; t += 256) Wl[t] = Wk[t];
  __syncthreads();
  int tid = threadIdx.x;
  int wid = tid >> 6, lane = tid & 63;
  int p = lane & 15, h = lane >> 4;
  int nwaves = gridDim.x * 4;
  for (int i = blockIdx.x * 4 + wid; i < NN; i += nwaves) {
    int s = i * CAP, e = rend[i];
    float ax = 0.f, ay = 0.f;
    for (int base = s; base < e; base += 64) {
      int idx = base + lane;
      int cl = (idx < e) ? colc[idx] : NN;  // sentinel -> zero row
      int m = e - base;
      if (m > 64) m = 64;
      for (int jj = 0; jj < m; jj += 32) {
#pragma unroll
        for (int q = 0; q < 8; ++q) {
          int j = jj + 4 * q + h;  // j < 64 always; overshoot lanes hold sentinel
          int cj = __shfl(cl, j);
          uintT r = U[(size_t)cj * 16 + p];
          ax += __uint_as_float(r << 16);
          ay += __uint_as_float(r & 0xffff0000u);
        }
      }
    }
    ax += __shfl_down(ax, 32); ay += __shfl_down(ay, 32);
    ax += __shfl_down(ax, 16); ay += __shfl_down(ay, 16);
    // lanes 0..15 hold channel-pair sums
    float di = dinv[i];
    float vx, vy;
    if (FIRST) {
      vx = -di * ax; vy = -di * ay;
    } else {
      uintT au = A[(size_t)i * 16 + p];
      vx = fmaf(-2.f * di, ax, -__uint_as_float(au << 16));
      vy = fmaf(-2.f * di, ay, -__uint_as_float(au & 0xffff0000u));
    }
    if (lane < 16) {
      C[(size_t)i * 16 + p] = pack2(vx, vy);
      Uo[(size_t)i * 16 + p] = pack2(di * vx, di * vy);
    }
    // fused acc += v @ Wk (v valid on lanes 0..15 as channel pairs)
    int hf = lane >> 5, j = lane & 31;
    float g = 0.f;
#pragma unroll
    for (int t = 0; t < 8; ++t) {
      int tt = hf * 8 + t;
      float vxx = __shfl(vx, tt);
      float vyy = __shfl(vy, tt);
      g = fmaf(vxx, Wl[(2 * tt) * NCH + j], g);
      g = fmaf(vyy, Wl[(2 * tt + 1) * NCH + j], g);
    }
    g += __shfl_down(g, 32);
    if (hf == 0) acc[(size_t)i * NCH + j] += g;
  }
}

__global__ __launch_bounds__(256) void silu_b16_k(const float* __restrict__ a,
                                                  const float* __restrict__ b,
                                                  const float* __restrict__ dinv,
                                                  ushortT* __restrict__ h,
                                                  ushortT* __restrict__ Uh) {
  int t = blockIdx.x * blockDim.x + threadIdx.x;
  if (t >= NN * NCH) return;
  float v = a[t] + b[t & 31];
  float sv = v / (1.f + expf(-v));
  h[t] = f2b(sv);
  Uh[t] = f2b(dinv[t >> 5] * sv);
}

__global__ __launch_bounds__(256) void final_kk(const ushortT* __restrict__ h,
                                                const float* __restrict__ W4,
                                                float* __restrict__ out) {
  __shared__ float Wl[32];
  if (threadIdx.x < 32) Wl[threadIdx.x] = W4[threadIdx.x];
  __syncthreads();
  int i = blockIdx.x * blockDim.x + threadIdx.x;
  if (i >= NN) return;
  const uintT* hr = (const uintT*)h + (size_t)i * 16;
  float g = 0.f;
#pragma unroll
  for (int p = 0; p < 16; ++p) {
    uintT u = hr[p];
    g = fmaf(__uint_as_float(u << 16), Wl[2 * p], g);
    g = fmaf(__uint_as_float(u & 0xffff0000u), Wl[2 * p + 1], g);
  }
  out[i] = g;
}

// ---------------- host ----------------

extern "C" void kernel_launch(void* const* d_in, const int* in_sizes, int n_in,
                              void* d_out, int out_size, void* d_ws, size_t ws_size,
                              hipStream_t stream) {
  const float* x = (const float*)d_in[0];
  const int* ei = (const int*)d_in[1];
  const float* W1 = (const float*)d_in[4];
  const float* b1 = (const float*)d_in[5];
  const float* W2 = (const float*)d_in[6];
  const float* b2 = (const float*)d_in[7];
  const float* W3 = (const float*)d_in[8];
  const float* b3 = (const float*)d_in[9];
  const float* W4 = (const float*)d_in[10];
  float* out = (float*)d_out;

  char* ws = (char*)d_ws;
  size_t off = 0;
  auto alloc = [&](size_t bytes) {
    void* p = ws + off;
    off += (bytes + 255) & ~(size_t)255;
    return p;
  };
  int* rend = (int*)alloc((size_t)NN * 4);          // cursor -> row end
  float* dinv = (float*)alloc((size_t)NN * 4);
  int* colc = (int*)alloc((size_t)NN * CAP * 4);    // padded CSR, 38.4 MB
  float4* Uxf = (float4*)alloc(((size_t)NN + 1) * 16);
  float4* Uaf = (float4*)alloc(((size_t)NN + 1) * 16);
  float4* Ubf = (float4*)alloc(((size_t)NN + 1) * 16);
  ushortT* Uh = (ushortT*)alloc(((size_t)NN + 1) * 64);
  ushortT* Ua16 = (ushortT*)alloc(((size_t)NN + 1) * 64);
  ushortT* Ub16 = (ushortT*)alloc(((size_t)NN + 1) * 64);
  ushortT* h1 = (ushortT*)alloc((size_t)NN * NCH * 2);
  ushortT* h2 = (ushortT*)alloc((size_t)NN * NCH * 2);
  float* Tall = (float*)alloc((size_t)23 * NN * 3 * 4);  // 27.6 MB, dead after gemm_l1
  ushortT* tC = (ushortT*)alloc((size_t)NN * NCH * 2);
  // overlays into Tall (live only during layers 2/3)
  float* acc = Tall;                                 // 12.8 MB
  ushortT* tA = (ushortT*)((char*)Tall + 12800000);  // 6.4 MB
  ushortT* tB = (ushortT*)((char*)Tall + 19200000);  // 6.4 MB
  ushortT* h3 = h1;                                  // h1 dead by then
  (void)ws_size; (void)in_sizes; (void)n_in; (void)out_size;

  const int GB = 2048;                     // wave-per-row grid (grid-stride)
  const int GE = (NN * NCH + 255) / 256;   // elementwise grids
  const int GR = (NN + 255) / 256;         // row grids
  const int GR8 = (NN * 8 + 255) / 256;    // 8-lanes-per-row grid

  // ---- padded CSR build (no histogram/scan) ----
  init_cursor_k<<<GR, 256, 0, stream>>>(rend);
  {
    int step = (NN + FILL_PASSES - 1) / FILL_PASSES;
    for (int p = 0; p < FILL_PASSES; ++p) {
      int lo = p * step;
      int hi = (lo + step < NN) ? lo + step : NN;
      fill_k<<<(EE / 4 + 255) / 256, 256, 0, stream>>>(ei, rend, colc, lo, hi);
    }
  }
  dinv_k<<<GR, 256, 0, stream>>>(rend, dinv);
  init_sent_k<<<1, 64, 0, stream>>>((uintT*)Uh, (uintT*)Ua16, (uintT*)Ub16, Uxf, Uaf, Ubf);

  auto Tp = [&](int k) { return Tall + (size_t)(k - 1) * NN * 3; };

  // ---- layer 1: K=24, F=3 -> 32 ----
  prescale_x_k<<<GR, 256, 0, stream>>>(x, dinv, Uxf);
  cheb_f3_k<true><<<GR8, 256, 0, stream>>>(rend, colc, dinv, Uxf, nullptr, Tp(1), Uaf);
  for (int k = 2; k < 24; ++k) {
    const float4* Ug = (k & 1) ? Ubf : Uaf;
    float4* Uw = (k & 1) ? Uaf : Ubf;
    const float* Apf = (k == 2) ? x : Tp(k - 2);
    cheb_f3_k<false><<<GR8, 256, 0, stream>>>(rend, colc, dinv, Ug, Apf, Tp(k), Uw);
  }
  gemm_l1_k<<<GE, 256, 0, stream>>>(x, Tall, W1, b1, dinv, h1, Uh);

  // ---- layers 2 & 3: K=12 / K=10, F=32 -> 32, bf16 prescaled-gather ----
  auto run_layer = [&](const ushortT* in, ushortT* hout, ushortT* Uhout,
                       const float* W, const float* b, int K) {
    gemm_k0_b16_k<<<GE, 256, 0, stream>>>(in, W, acc);
    cheb_b16_k<true><<<GB, 256, 0, stream>>>(rend, colc, dinv, (const uintT*)Uh,
                                             nullptr, (uintT*)tA, (uintT*)Ua16,
                                             acc, W + NCH * NCH);
    const uintT* Ap = (const uintT*)in;
    ushortT* Cprev = tA;
    ushortT* cyc[3] = {tB, tC, tA};
    for (int k = 2; k < K; ++k) {
      ushortT* Cp = cyc[(k - 2) % 3];
      const uintT* Ug = (k & 1) ? (const uintT*)Ub16 : (const uintT*)Ua16;
      uintT* Uw = (k & 1) ? (uintT*)Ua16 : (uintT*)Ub16;
      cheb_b16_k<false><<<GB, 256, 0, stream>>>(rend, colc, dinv, Ug, Ap,
                                                (uintT*)Cp, Uw, acc,
                                                W + (size_t)NCH * NCH * k);
      Ap = (const uintT*)Cprev;
      Cprev = Cp;
    }
    silu_b16_k<<<GE, 256, 0, stream>>>(acc, b, dinv, hout, Uhout);
  };
  run_layer(h1, h2, Uh, W2, b2, 12);
  run_layer(h2, h3, Uh, W3, b3, 10);

  // ---- layer 4: K=1, 32 -> 1, no bias ----
  final_kk<<<GR, 256, 0, stream>>>(h3, W4, out);
}

// Round 6
// 2173.254 us; speedup vs baseline: 1.0225x; 1.0225x over previous
//
#include <hip/hip_runtime.h>
#include <math.h>

#define NN 100000
#define EE 3200000
#define NCH 32
#define CAP 96          // padded CSR row capacity (deg~Poisson(32); P(>=96) ~ 5e-20)
#define FILL_PASSES 8

typedef unsigned short ushortT;
typedef unsigned int uintT;

__device__ __forceinline__ ushortT f2b(float f) {
  uintT u = __float_as_uint(f);
  uintT r = u + 0x7fffu + ((u >> 16) & 1u);  // RNE
  return (ushortT)(r >> 16);
}
__device__ __forceinline__ uintT pack2(float x, float y) {
  return (uintT)f2b(x) | ((uintT)f2b(y) << 16);
}
__device__ __forceinline__ float lo2f(uintT u) { return __uint_as_float(u << 16); }
__device__ __forceinline__ float hi2f(uintT u) { return __uint_as_float(u & 0xffff0000u); }

// ---------------- setup ----------------

__global__ void init_cursor_k(int* __restrict__ cur) {
  int i = blockIdx.x * blockDim.x + threadIdx.x;
  if (i < NN) cur[i] = i * CAP;
}

__global__ void fill_k(const int* __restrict__ ei, int* __restrict__ cursor,
                       int* __restrict__ colc, int lo, int hi) {
  int t = blockIdx.x * blockDim.x + threadIdx.x;
  if (t * 4 >= EE) return;
  int4 r4 = ((const int4*)ei)[t];
  int4 c4 = ((const int4*)(ei + EE))[t];
  if (r4.x != c4.x && r4.x >= lo && r4.x < hi) colc[atomicAdd(&cursor[r4.x], 1)] = c4.x;
  if (r4.y != c4.y && r4.y >= lo && r4.y < hi) colc[atomicAdd(&cursor[r4.y], 1)] = c4.y;
  if (r4.z != c4.z && r4.z >= lo && r4.z < hi) colc[atomicAdd(&cursor[r4.z], 1)] = c4.z;
  if (r4.w != c4.w && r4.w >= lo && r4.w < hi) colc[atomicAdd(&cursor[r4.w], 1)] = c4.w;
}

// degree -> dinv, dinv^2, sqd (=sqrt(deg), 1 if deg==0)
__global__ void dinv_k(const int* __restrict__ rend, float* __restrict__ dinv,
                       float* __restrict__ d2, float* __restrict__ sqd) {
  int i = blockIdx.x * blockDim.x + threadIdx.x;
  if (i >= NN) return;
  int c = rend[i] - i * CAP;
  float di = (c > 0) ? rsqrtf((float)c) : 0.f;
  dinv[i] = di;
  d2[i] = di * di;
  sqd[i] = (c > 0) ? sqrtf((float)c) : 1.f;
}

// zero sentinel row NN of the 24 f3 V-planes (float4 each)
__global__ void sent_f3_k(float4* __restrict__ Vf) {
  int t = threadIdx.x;
  if (t < 24) Vf[(size_t)t * (NN + 1) + NN] = make_float4(0.f, 0.f, 0.f, 0.f);
}

// zero sentinel rows of the six 16-ch bf16 tables (8 dwords each)
__global__ void sent_b16_k(uintT* Vh0, uintT* Vh1, uintT* Va0, uintT* Va1,
                           uintT* Vb0, uintT* Vb1) {
  int t = threadIdx.x;
  if (t < 8) {
    Vh0[(size_t)NN * 8 + t] = 0u;
    Vh1[(size_t)NN * 8 + t] = 0u;
    Va0[(size_t)NN * 8 + t] = 0u;
    Va1[(size_t)NN * 8 + t] = 0u;
    Vb0[(size_t)NN * 8 + t] = 0u;
    Vb1[(size_t)NN * 8 + t] = 0u;
  }
}

// Vf[0] = dinv * x (padded float4)
__global__ __launch_bounds__(256) void prescale_x_k(const float* __restrict__ x,
                                                    const float* __restrict__ dinv,
                                                    float4* __restrict__ V0) {
  int i = blockIdx.x * blockDim.x + threadIdx.x;
  if (i >= NN) return;
  float di = dinv[i];
  V0[i] = make_float4(di * x[3 * i], di * x[3 * i + 1], di * x[3 * i + 2], 0.f);
}

// ---------------- layer kernels ----------------

// 8 lanes/row, F=3, V-space recurrence: V_k = (FIRST ? -d2*S : -2*d2*S - Vprev2)
template <bool FIRST>
__global__ __launch_bounds__(256) void cheb_f3_k(
    const int* __restrict__ rend, const int* __restrict__ colc,
    const float* __restrict__ d2, const float4* __restrict__ U,
    const float4* __restrict__ A, float4* __restrict__ Vo) {
  int t8 = blockIdx.x * blockDim.x + threadIdx.x;
  int i = t8 >> 3, q = t8 & 7;
  if (i >= NN) return;
  int s = i * CAP, e = rend[i];
  float a0 = 0.f, a1 = 0.f, a2 = 0.f;
  for (int t = s + q; t < e; t += 32) {
#pragma unroll
    for (int u = 0; u < 4; ++u) {
      int tt = t + 8 * u;
      int cc = (tt < e) ? colc[tt] : NN;  // sentinel row NN is zero
      float4 r = U[cc];
      a0 += r.x; a1 += r.y; a2 += r.z;
    }
  }
  a0 += __shfl_xor(a0, 1); a1 += __shfl_xor(a1, 1); a2 += __shfl_xor(a2, 1);
  a0 += __shfl_xor(a0, 2); a1 += __shfl_xor(a1, 2); a2 += __shfl_xor(a2, 2);
  a0 += __shfl_xor(a0, 4); a1 += __shfl_xor(a1, 4); a2 += __shfl_xor(a2, 4);
  if (q == 0) {
    float d2i = d2[i];
    float4 vo;
    if (FIRST) {
      vo = make_float4(-d2i * a0, -d2i * a1, -d2i * a2, 0.f);
    } else {
      float4 ap = A[i];
      vo = make_float4(fmaf(-2.f * d2i, a0, -ap.x),
                       fmaf(-2.f * d2i, a1, -ap.y),
                       fmaf(-2.f * d2i, a2, -ap.z), 0.f);
    }
    Vo[i] = vo;
  }
}

// Layer-1 GEMM over x + 23 V-planes (T_k = sqd*V_k) + bias + SiLU
// -> h1 (bf16 compact) and Vh halves (dinv-prescaled bf16)
__global__ __launch_bounds__(256) void gemm_l1_k(
    const float* __restrict__ x, const float4* __restrict__ Vf,
    const float* __restrict__ W1, const float* __restrict__ b1,
    const float* __restrict__ dinv, const float* __restrict__ sqd,
    ushortT* __restrict__ h1, ushortT* __restrict__ Vh0,
    ushortT* __restrict__ Vh1) {
  __shared__ float Wl[24 * 96];
  for (int t = threadIdx.x; t < 24 * 96; t += 256) Wl[t] = W1[t];
  __syncthreads();
  int t = blockIdx.x * blockDim.x + threadIdx.x;
  if (t >= NN * NCH) return;
  int i = t >> 5, j = t & 31;
  float gs = 0.f;
#pragma unroll
  for (int k = 1; k < 24; ++k) {
    float4 v = Vf[(size_t)k * (NN + 1) + i];
    gs = fmaf(v.x, Wl[k * 96 + j],
         fmaf(v.y, Wl[k * 96 + 32 + j], fmaf(v.z, Wl[k * 96 + 64 + j], gs)));
  }
  float g = b1[j];
  g = fmaf(x[i * 3 + 0], Wl[j],
      fmaf(x[i * 3 + 1], Wl[32 + j], fmaf(x[i * 3 + 2], Wl[64 + j], g)));
  g = fmaf(sqd[i], gs, g);
  float sv = g / (1.f + expf(-g));
  h1[t] = f2b(sv);
  ushortT uv = f2b(dinv[i] * sv);
  if (j < 16) Vh0[(size_t)i * 16 + j] = uv;
  else        Vh1[(size_t)i * 16 + (j - 16)] = uv;
}

// k=0 term split by input half: accP0 = h[:,0:16]@W0[0:16,:], accP1 likewise
__global__ __launch_bounds__(256) void gemm_k0_b16_k(const ushortT* __restrict__ in,
                                                     const float* __restrict__ W,
                                                     float* __restrict__ accP0,
                                                     float* __restrict__ accP1) {
  __shared__ float Wl[NCH * NCH];
  for (int t = threadIdx.x; t < NCH * NCH; t += 256) Wl[t] = W[t];
  __syncthreads();
  int t = blockIdx.x * blockDim.x + threadIdx.x;
  if (t >= NN * NCH) return;
  int i = t >> 5, j = t & 31;
  const uintT* bi = (const uintT*)in + (size_t)i * 16;
  float g0 = 0.f, g1 = 0.f;
#pragma unroll
  for (int p = 0; p < 8; ++p) {
    uintT u = bi[p];
    g0 = fmaf(lo2f(u), Wl[(2 * p) * NCH + j], g0);
    g0 = fmaf(hi2f(u), Wl[(2 * p + 1) * NCH + j], g0);
  }
#pragma unroll
  for (int p = 8; p < 16; ++p) {
    uintT u = bi[p];
    g1 = fmaf(lo2f(u), Wl[(2 * p) * NCH + j], g1);
    g1 = fmaf(hi2f(u), Wl[(2 * p + 1) * NCH + j], g1);
  }
  accP0[t] = g0;
  accP1[t] = g1;
}

// One wave per row, 16-channel half pass. Gather table U: (NN+1) x 8 dwords
// (3.2MB -> L2-resident). V_k = (FIRST ? -d2*S : -2*d2*S - Ap).
// accP += sqd * (V_k @ Wk_half). Wk points at the 16x32 half of W[k].
template <bool FIRST>
__global__ __launch_bounds__(256) void cheb_b16_k(
    const int* __restrict__ rend, const int* __restrict__ colc,
    const float* __restrict__ d2, const float* __restrict__ sqd,
    const uintT* __restrict__ U, const uintT* __restrict__ Ap,
    uintT* __restrict__ Vo, float* __restrict__ accP,
    const float* __restrict__ Wk) {
  __shared__ float Wl[16 * NCH];
  for (int t = threadIdx.x; t < 16 * NCH; t += 256) Wl[t] = Wk[t];
  __syncthreads();
  int tid = threadIdx.x;
  int wid = tid >> 6, lane = tid & 63;
  int p = lane & 7, h = lane >> 3;
  int nwaves = gridDim.x * 4;
  for (int i = blockIdx.x * 4 + wid; i < NN; i += nwaves) {
    int s = i * CAP, e = rend[i];
    float ax = 0.f, ay = 0.f;
    for (int base = s; base < e; base += 64) {
      int idx = base + lane;
      int cl = (idx < e) ? colc[idx] : NN;  // sentinel -> zero row
      if (e - base > 32) {
#pragma unroll
        for (int q = 0; q < 8; ++q) {
          int j = q * 8 + h;
          int cj = __shfl(cl, j);
          uintT r = U[(size_t)cj * 8 + p];
          ax += lo2f(r); ay += hi2f(r);
        }
      } else {
#pragma unroll
        for (int q = 0; q < 4; ++q) {
          int j = q * 8 + h;
          int cj = __shfl(cl, j);
          uintT r = U[(size_t)cj * 8 + p];
          ax += lo2f(r); ay += hi2f(r);
        }
      }
    }
    ax += __shfl_down(ax, 32); ay += __shfl_down(ay, 32);
    ax += __shfl_down(ax, 16); ay += __shfl_down(ay, 16);
    ax += __shfl_down(ax, 8);  ay += __shfl_down(ay, 8);
    // lanes 0..7 hold channel-pair sums for dword p
    float d2i = d2[i];
    float vx, vy;
    if (FIRST) {
      vx = -d2i * ax; vy = -d2i * ay;
    } else {
      uintT au = (lane < 8) ? Ap[(size_t)i * 8 + p] : 0u;
      vx = fmaf(-2.f * d2i, ax, -lo2f(au));
      vy = fmaf(-2.f * d2i, ay, -hi2f(au));
    }
    if (lane < 8) Vo[(size_t)i * 8 + p] = pack2(vx, vy);
    // fused accP += sqd * (v @ Wk)
    int hf = lane >> 5, j = lane & 31;
    float g = 0.f;
#pragma unroll
    for (int t = 0; t < 4; ++t) {
      int tt = hf * 4 + t;
      float vxx = __shfl(vx, tt);
      float vyy = __shfl(vy, tt);
      g = fmaf(vxx, Wl[(2 * tt) * NCH + j], g);
      g = fmaf(vyy, Wl[(2 * tt + 1) * NCH + j], g);
    }
    g += __shfl_down(g, 32);
    if (hf == 0) accP[(size_t)i * NCH + j] += g * sqd[i];
  }
}

__global__ __launch_bounds__(256) void silu_b16_k(const float* __restrict__ a0,
                                                  const float* __restrict__ a1,
                                                  const float* __restrict__ b,
                                                  const float* __restrict__ dinv,
                                                  ushortT* __restrict__ h,
                                                  ushortT* __restrict__ Vh0,
                                                  ushortT* __restrict__ Vh1) {
  int t = blockIdx.x * blockDim.x + threadIdx.x;
  if (t >= NN * NCH) return;
  int i = t >> 5, j = t & 31;
  float v = a0[t] + a1[t] + b[j];
  float sv = v / (1.f + expf(-v));
  h[t] = f2b(sv);
  ushortT uv = f2b(dinv[i] * sv);
  if (j < 16) Vh0[(size_t)i * 16 + j] = uv;
  else        Vh1[(size_t)i * 16 + (j - 16)] = uv;
}

__global__ __launch_bounds__(256) void final_kk(const ushortT* __restrict__ h,
                                                const float* __restrict__ W4,
                                                float* __restrict__ out) {
  __shared__ float Wl[32];
  if (threadIdx.x < 32) Wl[threadIdx.x] = W4[threadIdx.x];
  __syncthreads();
  int i = blockIdx.x * blockDim.x + threadIdx.x;
  if (i >= NN) return;
  const uintT* hr = (const uintT*)h + (size_t)i * 16;
  float g = 0.f;
#pragma unroll
  for (int p = 0; p < 16; ++p) {
    uintT u = hr[p];
    g = fmaf(lo2f(u), Wl[2 * p], g);
    g = fmaf(hi2f(u), Wl[2 * p + 1], g);
  }
  out[i] = g;
}

// ---------------- host ----------------

extern "C" void kernel_launch(void* const* d_in, const int* in_sizes, int n_in,
                              void* d_out, int out_size, void* d_ws, size_t ws_size,
                              hipStream_t stream) {
  const float* x = (const float*)d_in[0];
  const int* ei = (const int*)d_in[1];
  const float* W1 = (const float*)d_in[4];
  const float* b1 = (const float*)d_in[5];
  const float* W2 = (const float*)d_in[6];
  const float* b2 = (const float*)d_in[7];
  const float* W3 = (const float*)d_in[8];
  const float* b3 = (const float*)d_in[9];
  const float* W4 = (const float*)d_in[10];
  float* out = (float*)d_out;

  char* ws = (char*)d_ws;
  size_t off = 0;
  auto alloc = [&](size_t bytes) {
    void* p = ws + off;
    off += (bytes + 255) & ~(size_t)255;
    return p;
  };
  int* rend = (int*)alloc((size_t)NN * 4);
  float* dinv = (float*)alloc((size_t)NN * 4);
  float* d2 = (float*)alloc((size_t)NN * 4);
  float* sqd = (float*)alloc((size_t)NN * 4);
  int* colc = (int*)alloc((size_t)NN * CAP * 4);         // 38.4 MB padded CSR
  ushortT* h1 = (ushortT*)alloc((size_t)NN * NCH * 2);
  ushortT* h2 = (ushortT*)alloc((size_t)NN * NCH * 2);
  ushortT* Vh0 = (ushortT*)alloc(((size_t)NN + 1) * 32);  // 16ch bf16 tables
  ushortT* Vh1 = (ushortT*)alloc(((size_t)NN + 1) * 32);
  // overlay region R: layer1 V-planes  OR  layer2/3 {Va*,Vb*,accP*}
  size_t vf_bytes = (size_t)24 * (NN + 1) * 16;           // 38,400,384
  size_t l23_bytes = 2 * 12800256 + 4 * 3200256;          // 38,401,536
  char* R = (char*)alloc(vf_bytes > l23_bytes ? vf_bytes : l23_bytes);
  float4* Vf = (float4*)R;
  float* accP0 = (float*)R;
  float* accP1 = (float*)(R + 12800256);
  ushortT* Va0 = (ushortT*)(R + 2 * 12800256);
  ushortT* Va1 = (ushortT*)(R + 2 * 12800256 + 3200256);
  ushortT* Vb0 = (ushortT*)(R + 2 * 12800256 + 2 * 3200256);
  ushortT* Vb1 = (ushortT*)(R + 2 * 12800256 + 3 * 3200256);
  ushortT* h3 = h1;  // h1 dead after layer-2 gemm_k0
  (void)ws_size; (void)in_sizes; (void)n_in; (void)out_size;

  const int GB = 2048;
  const int GE = (NN * NCH + 255) / 256;
  const int GR = (NN + 255) / 256;
  const int GR8 = (NN * 8 + 255) / 256;

  // ---- padded CSR build ----
  init_cursor_k<<<GR, 256, 0, stream>>>(rend);
  {
    int step = (NN + FILL_PASSES - 1) / FILL_PASSES;
    for (int p = 0; p < FILL_PASSES; ++p) {
      int lo = p * step;
      int hi = (lo + step < NN) ? lo + step : NN;
      fill_k<<<(EE / 4 + 255) / 256, 256, 0, stream>>>(ei, rend, colc, lo, hi);
    }
  }
  dinv_k<<<GR, 256, 0, stream>>>(rend, dinv, d2, sqd);

  // ---- layer 1: K=24, F=3 -> 32 (V-plane storage) ----
  sent_f3_k<<<1, 64, 0, stream>>>(Vf);
  prescale_x_k<<<GR, 256, 0, stream>>>(x, dinv, Vf);
  auto Vp = [&](int k) { return Vf + (size_t)k * (NN + 1); };
  cheb_f3_k<true><<<GR8, 256, 0, stream>>>(rend, colc, d2, Vp(0), nullptr, Vp(1));
  for (int k = 2; k < 24; ++k)
    cheb_f3_k<false><<<GR8, 256, 0, stream>>>(rend, colc, d2, Vp(k - 1), Vp(k - 2), Vp(k));
  gemm_l1_k<<<GE, 256, 0, stream>>>(x, Vf, W1, b1, dinv, sqd, h1, Vh0, Vh1);

  // ---- layers 2 & 3: 16-channel half passes, L2-resident gather tables ----
  sent_b16_k<<<1, 64, 0, stream>>>((uintT*)Vh0, (uintT*)Vh1, (uintT*)Va0,
                                   (uintT*)Va1, (uintT*)Vb0, (uintT*)Vb1);
  uintT* tbl[3][2] = {{(uintT*)Vh0, (uintT*)Vh1},
                      {(uintT*)Va0, (uintT*)Va1},
                      {(uintT*)Vb0, (uintT*)Vb1}};
  float* accs[2] = {accP0, accP1};
  auto run_layer = [&](const ushortT* in, ushortT* hout, const float* W,
                       const float* b, int K) {
    gemm_k0_b16_k<<<GE, 256, 0, stream>>>(in, W, accP0, accP1);
    for (int P = 0; P < 2; ++P)
      cheb_b16_k<true><<<GB, 256, 0, stream>>>(rend, colc, d2, sqd, tbl[0][P],
                                               nullptr, tbl[1][P], accs[P],
                                               W + 1024 + P * 512);
    for (int k = 2; k < K; ++k) {
      for (int P = 0; P < 2; ++P)
        cheb_b16_k<false><<<GB, 256, 0, stream>>>(
            rend, colc, d2, sqd, tbl[(k - 1) % 3][P], tbl[(k - 2) % 3][P],
            tbl[k % 3][P], accs[P], W + (size_t)k * 1024 + P * 512);
    }
    silu_b16_k<<<GE, 256, 0, stream>>>(accP0, accP1, b, dinv, hout, Vh0, Vh1);
  };
  run_layer(h1, h2, W2, b2, 12);
  run_layer(h2, h3, W3, b3, 10);

  // ---- layer 4 ----
  final_kk<<<GR, 256, 0, stream>>>(h3, W4, out);
}

// Round 7
// 1929.838 us; speedup vs baseline: 1.1515x; 1.1261x over previous
//
#include <hip/hip_runtime.h>
#include <math.h>

#define NN 100000
#define EE 3200000
#define NCH 32
#define CAP 96          // padded CSR row capacity (deg~Poisson(32); P(>=96)~5e-20)
#define FILL_PASSES 8
#define HB 3200256      // aligned bytes per 16-channel bf16 half-table ((NN+1)*32 -> 256-pad)

typedef unsigned short ushortT;
typedef unsigned int uintT;

__device__ __forceinline__ ushortT f2b(float f) {
  uintT u = __float_as_uint(f);
  uintT r = u + 0x7fffu + ((u >> 16) & 1u);  // RNE
  return (ushortT)(r >> 16);
}
__device__ __forceinline__ uintT pack2(float x, float y) {
  return (uintT)f2b(x) | ((uintT)f2b(y) << 16);
}
__device__ __forceinline__ float lo2f(uintT u) { return __uint_as_float(u << 16); }
__device__ __forceinline__ float hi2f(uintT u) { return __uint_as_float(u & 0xffff0000u); }
__device__ __forceinline__ float silu(float v) { return v / (1.f + expf(-v)); }

// ---------------- setup ----------------

__global__ void init_cursor_k(int* __restrict__ cur) {
  int i = blockIdx.x * blockDim.x + threadIdx.x;
  if (i < NN) cur[i] = i * CAP;
}

__global__ void fill_k(const int* __restrict__ ei, int* __restrict__ cursor,
                       int* __restrict__ colc, int lo, int hi) {
  int t = blockIdx.x * blockDim.x + threadIdx.x;
  if (t * 4 >= EE) return;
  int4 r4 = ((const int4*)ei)[t];
  int4 c4 = ((const int4*)(ei + EE))[t];
  if (r4.x != c4.x && r4.x >= lo && r4.x < hi) colc[atomicAdd(&cursor[r4.x], 1)] = c4.x;
  if (r4.y != c4.y && r4.y >= lo && r4.y < hi) colc[atomicAdd(&cursor[r4.y], 1)] = c4.y;
  if (r4.z != c4.z && r4.z >= lo && r4.z < hi) colc[atomicAdd(&cursor[r4.z], 1)] = c4.z;
  if (r4.w != c4.w && r4.w >= lo && r4.w < hi) colc[atomicAdd(&cursor[r4.w], 1)] = c4.w;
}

__global__ void dinv_k(const int* __restrict__ rend, float* __restrict__ dinv,
                       float* __restrict__ d2, float* __restrict__ sqd) {
  int i = blockIdx.x * blockDim.x + threadIdx.x;
  if (i >= NN) return;
  int c = rend[i] - i * CAP;
  float di = (c > 0) ? rsqrtf((float)c) : 0.f;
  dinv[i] = di;
  d2[i] = di * di;
  sqd[i] = (c > 0) ? sqrtf((float)c) : 1.f;
}

// zero sentinel row NN of the 24 layer-1 float4 V-planes
__global__ void sent_f3_k(float4* __restrict__ Vf) {
  int t = threadIdx.x;
  if (t < 24) Vf[(size_t)t * (NN + 1) + NN] = make_float4(0.f, 0.f, 0.f, 0.f);
}

// zero sentinel rows of Vh halves + 12 ring half-tables (after layer 1)
__global__ void sent_b16_k(uintT* __restrict__ Vh0, uintT* __restrict__ Vh1,
                           char* __restrict__ R) {
  int t = threadIdx.x;  // 14 tables x 8 dwords = 112 threads
  int tb = t >> 3, d = t & 7;
  if (tb >= 14) return;
  uintT* base;
  if (tb == 12) base = Vh0;
  else if (tb == 13) base = Vh1;
  else base = (uintT*)(R + (size_t)tb * HB);
  base[(size_t)NN * 8 + d] = 0u;
}

// Vf plane 0 = dinv * x (padded float4)
__global__ __launch_bounds__(256) void prescale_x_k(const float* __restrict__ x,
                                                    const float* __restrict__ dinv,
                                                    float4* __restrict__ V0) {
  int i = blockIdx.x * blockDim.x + threadIdx.x;
  if (i >= NN) return;
  float di = dinv[i];
  V0[i] = make_float4(di * x[3 * i], di * x[3 * i + 1], di * x[3 * i + 2], 0.f);
}

// ---------------- layer 1 ----------------

// 8 lanes/row, F=3, V-space recurrence
template <bool FIRST>
__global__ __launch_bounds__(256) void cheb_f3_k(
    const int* __restrict__ rend, const int* __restrict__ colc,
    const float* __restrict__ d2, const float4* __restrict__ U,
    const float4* __restrict__ A, float4* __restrict__ Vo) {
  int t8 = blockIdx.x * blockDim.x + threadIdx.x;
  int i = t8 >> 3, q = t8 & 7;
  if (i >= NN) return;
  int s = i * CAP, e = rend[i];
  float a0 = 0.f, a1 = 0.f, a2 = 0.f;
  for (int t = s + q; t < e; t += 32) {
#pragma unroll
    for (int u = 0; u < 4; ++u) {
      int tt = t + 8 * u;
      int cc = (tt < e) ? colc[tt] : NN;  // sentinel row NN is zero
      float4 r = U[cc];
      a0 += r.x; a1 += r.y; a2 += r.z;
    }
  }
  a0 += __shfl_xor(a0, 1); a1 += __shfl_xor(a1, 1); a2 += __shfl_xor(a2, 1);
  a0 += __shfl_xor(a0, 2); a1 += __shfl_xor(a1, 2); a2 += __shfl_xor(a2, 2);
  a0 += __shfl_xor(a0, 4); a1 += __shfl_xor(a1, 4); a2 += __shfl_xor(a2, 4);
  if (q == 0) {
    float d2i = d2[i];
    float4 vo;
    if (FIRST) {
      vo = make_float4(-d2i * a0, -d2i * a1, -d2i * a2, 0.f);
    } else {
      float4 ap = A[i];
      vo = make_float4(fmaf(-2.f * d2i, a0, -ap.x),
                       fmaf(-2.f * d2i, a1, -ap.y),
                       fmaf(-2.f * d2i, a2, -ap.z), 0.f);
    }
    Vo[i] = vo;
  }
}

// thread-per-row; W1 via wave-uniform (SGPR) loads; silu fused.
// Writes only Vh = dinv*h1 (ring k=0 of layer 2).
__global__ __launch_bounds__(256) void gemm_l1_k(
    const float* __restrict__ x, const float4* __restrict__ Vf,
    const float* __restrict__ W1, const float* __restrict__ b1,
    const float* __restrict__ dinv, const float* __restrict__ sqd,
    ushortT* __restrict__ Vh0, ushortT* __restrict__ Vh1) {
  int i = blockIdx.x * blockDim.x + threadIdx.x;
  if (i >= NN) return;
  float s_[32];
#pragma unroll
  for (int j = 0; j < 32; ++j) s_[j] = 0.f;
#pragma unroll
  for (int k = 1; k < 24; ++k) {
    float4 v = Vf[(size_t)k * (NN + 1) + i];
    const float* Wk = W1 + k * 96;
#pragma unroll
    for (int j = 0; j < 32; ++j)
      s_[j] = fmaf(v.x, Wk[j], fmaf(v.y, Wk[32 + j], fmaf(v.z, Wk[64 + j], s_[j])));
  }
  float x0 = x[3 * i], x1 = x[3 * i + 1], x2 = x[3 * i + 2];
  float sq = sqd[i], di = dinv[i];
  uintT o0[8], o1[8];
#pragma unroll
  for (int p = 0; p < 16; ++p) {
    int j0 = 2 * p, j1 = 2 * p + 1;
    float g0 = fmaf(sq, s_[j0],
        fmaf(x0, W1[j0], fmaf(x1, W1[32 + j0], fmaf(x2, W1[64 + j0], b1[j0]))));
    float g1 = fmaf(sq, s_[j1],
        fmaf(x0, W1[j1], fmaf(x1, W1[32 + j1], fmaf(x2, W1[64 + j1], b1[j1]))));
    uintT u = pack2(di * silu(g0), di * silu(g1));
    if (p < 8) o0[p] = u; else o1[p - 8] = u;
  }
  uint4* w0 = (uint4*)((uintT*)Vh0 + (size_t)i * 8);
  uint4* w1 = (uint4*)((uintT*)Vh1 + (size_t)i * 8);
  w0[0] = make_uint4(o0[0], o0[1], o0[2], o0[3]);
  w0[1] = make_uint4(o0[4], o0[5], o0[6], o0[7]);
  w1[0] = make_uint4(o1[0], o1[1], o1[2], o1[3]);
  w1[1] = make_uint4(o1[4], o1[5], o1[6], o1[7]);
}

// ---------------- layers 2/3 ----------------

// Pure gather Chebyshev half-step. 8 lanes/row, lane g owns channel-pair g.
// No reduction, no LDS, no acc.
template <bool FIRST>
__global__ __launch_bounds__(256) void cheb_bh_k(
    const int* __restrict__ rend, const int* __restrict__ colc,
    const float* __restrict__ d2, const uintT* __restrict__ U,
    const uintT* __restrict__ Ap, uintT* __restrict__ Vo) {
  int t = blockIdx.x * blockDim.x + threadIdx.x;
  int i = t >> 3;
  if (i >= NN) return;
  int g = t & 7;
  int lb = (threadIdx.x & 63) & 56;  // 8-lane group base within wave
  int s = i * CAP, e = rend[i];
  float ax = 0.f, ay = 0.f;
  for (int b = s; b < e; b += 8) {
    int idx = b + g;
    int cl = (idx < e) ? colc[idx] : NN;  // sentinel -> zero row
#pragma unroll
    for (int u = 0; u < 8; ++u) {
      int cj = __shfl(cl, lb + u);
      uintT r = U[(size_t)cj * 8 + g];
      ax += lo2f(r); ay += hi2f(r);
    }
  }
  float d2i = d2[i];
  float vx, vy;
  if (FIRST) {
    vx = -d2i * ax; vy = -d2i * ay;
  } else {
    uintT au = Ap[(size_t)i * 8 + g];
    vx = fmaf(-2.f * d2i, ax, -lo2f(au));
    vy = fmaf(-2.f * d2i, ay, -hi2f(au));
  }
  Vo[(size_t)i * 8 + g] = pack2(vx, vy);
}

__device__ __forceinline__ void fma_pair(uintT dw, const float* __restrict__ Wc,
                                         float a[32]) {
  float vl = lo2f(dw), vh = hi2f(dw);
#pragma unroll
  for (int j = 0; j < 32; ++j) a[j] = fmaf(vl, Wc[j], a[j]);
#pragma unroll
  for (int j = 0; j < 32; ++j) a[j] = fmaf(vh, Wc[32 + j], a[j]);
}

__device__ __forceinline__ void plane_fma(const uintT* __restrict__ h0,
                                          const uintT* __restrict__ h1, size_t i,
                                          const float* __restrict__ W, float a[32]) {
  uint4 u0 = *(const uint4*)(h0 + i * 8);
  uint4 u1 = *(const uint4*)(h0 + i * 8 + 4);
  uint4 u2 = *(const uint4*)(h1 + i * 8);
  uint4 u3 = *(const uint4*)(h1 + i * 8 + 4);
  fma_pair(u0.x, W + 0 * 64, a);   fma_pair(u0.y, W + 1 * 64, a);
  fma_pair(u0.z, W + 2 * 64, a);   fma_pair(u0.w, W + 3 * 64, a);
  fma_pair(u1.x, W + 4 * 64, a);   fma_pair(u1.y, W + 5 * 64, a);
  fma_pair(u1.z, W + 6 * 64, a);   fma_pair(u1.w, W + 7 * 64, a);
  fma_pair(u2.x, W + 8 * 64, a);   fma_pair(u2.y, W + 9 * 64, a);
  fma_pair(u2.z, W + 10 * 64, a);  fma_pair(u2.w, W + 11 * 64, a);
  fma_pair(u3.x, W + 12 * 64, a);  fma_pair(u3.y, W + 13 * 64, a);
  fma_pair(u3.z, W + 14 * 64, a);  fma_pair(u3.w, W + 15 * 64, a);
}

// chunk GEMM: acc(+)= sum over NP planes of V_k @ W[k]. thread-per-row, SGPR W.
template <int NP, bool INIT>
__global__ __launch_bounds__(256) void gemm_ch_k(
    const uintT* __restrict__ A0, const uintT* __restrict__ A1,
    const uintT* __restrict__ B0, const uintT* __restrict__ B1,
    const float* __restrict__ W, float* __restrict__ acc) {
  int i = blockIdx.x * blockDim.x + threadIdx.x;
  if (i >= NN) return;
  float a[32];
  float4* ar = (float4*)(acc + (size_t)i * 32);
  if (INIT) {
#pragma unroll
    for (int j = 0; j < 32; ++j) a[j] = 0.f;
  } else {
#pragma unroll
    for (int q = 0; q < 8; ++q) {
      float4 v = ar[q];
      a[4 * q] = v.x; a[4 * q + 1] = v.y; a[4 * q + 2] = v.z; a[4 * q + 3] = v.w;
    }
  }
  plane_fma(A0, A1, (size_t)i, W, a);
  if (NP == 2) plane_fma(B0, B1, (size_t)i, W + 1024, a);
#pragma unroll
  for (int q = 0; q < 8; ++q)
    ar[q] = make_float4(a[4 * q], a[4 * q + 1], a[4 * q + 2], a[4 * q + 3]);
}

// layer transition: h = silu(sqd*acc + b); Vh = dinv*h
__global__ __launch_bounds__(256) void silu2_k(const float* __restrict__ acc,
                                               const float* __restrict__ b,
                                               const float* __restrict__ sqd,
                                               const float* __restrict__ dinv,
                                               ushortT* __restrict__ Vh0,
                                               ushortT* __restrict__ Vh1) {
  int t = blockIdx.x * blockDim.x + threadIdx.x;
  if (t >= NN * NCH) return;
  int i = t >> 5, j = t & 31;
  float g = fmaf(sqd[i], acc[t], b[j]);
  ushortT uv = f2b(dinv[i] * silu(g));
  if (j < 16) Vh0[(size_t)i * 16 + j] = uv;
  else        Vh1[(size_t)i * 16 + (j - 16)] = uv;
}

// final: out[i] = silu(sqd*acc + b3) . W4
__global__ __launch_bounds__(256) void final2_k(const float* __restrict__ acc,
                                                const float* __restrict__ b3,
                                                const float* __restrict__ sqd,
                                                const float* __restrict__ W4,
                                                float* __restrict__ out) {
  int i = blockIdx.x * blockDim.x + threadIdx.x;
  if (i >= NN) return;
  const float4* ar = (const float4*)(acc + (size_t)i * 32);
  float sq = sqd[i];
  float g = 0.f;
#pragma unroll
  for (int q = 0; q < 8; ++q) {
    float4 v = ar[q];
    g = fmaf(silu(fmaf(sq, v.x, b3[4 * q + 0])), W4[4 * q + 0], g);
    g = fmaf(silu(fmaf(sq, v.y, b3[4 * q + 1])), W4[4 * q + 1], g);
    g = fmaf(silu(fmaf(sq, v.z, b3[4 * q + 2])), W4[4 * q + 2], g);
    g = fmaf(silu(fmaf(sq, v.w, b3[4 * q + 3])), W4[4 * q + 3], g);
  }
  out[i] = g;
}

// ---------------- host ----------------

extern "C" void kernel_launch(void* const* d_in, const int* in_sizes, int n_in,
                              void* d_out, int out_size, void* d_ws, size_t ws_size,
                              hipStream_t stream) {
  const float* x = (const float*)d_in[0];
  const int* ei = (const int*)d_in[1];
  const float* W1 = (const float*)d_in[4];
  const float* b1 = (const float*)d_in[5];
  const float* W2 = (const float*)d_in[6];
  const float* b2 = (const float*)d_in[7];
  const float* W3 = (const float*)d_in[8];
  const float* b3 = (const float*)d_in[9];
  const float* W4 = (const float*)d_in[10];
  float* out = (float*)d_out;

  char* ws = (char*)d_ws;
  size_t off = 0;
  auto alloc = [&](size_t bytes) {
    void* p = ws + off;
    off += (bytes + 255) & ~(size_t)255;
    return p;
  };
  int* rend = (int*)alloc((size_t)NN * 4);
  float* dinv = (float*)alloc((size_t)NN * 4);
  float* d2 = (float*)alloc((size_t)NN * 4);
  float* sqd = (float*)alloc((size_t)NN * 4);
  int* colc = (int*)alloc((size_t)NN * CAP * 4);       // 38.4 MB padded CSR
  ushortT* Vh0 = (ushortT*)alloc(HB);                  // layer-input V halves
  ushortT* Vh1 = (ushortT*)alloc(HB);
  float* acc = (float*)alloc((size_t)NN * NCH * 4);    // 12.8 MB fp32 accumulator
  char* R = (char*)alloc((size_t)12 * HB);             // ring of 6 half-pairs / layer-1 Vf
  float4* Vf = (float4*)R;
  (void)ws_size; (void)in_sizes; (void)n_in; (void)out_size;

  const int GR = (NN + 255) / 256;        // thread-per-row grids
  const int GE = (NN * NCH + 255) / 256;  // element grids
  const int GR8 = (NN * 8 + 255) / 256;   // 8-lanes-per-row grids

  // ---- padded CSR build ----
  init_cursor_k<<<GR, 256, 0, stream>>>(rend);
  {
    int step = (NN + FILL_PASSES - 1) / FILL_PASSES;
    for (int p = 0; p < FILL_PASSES; ++p) {
      int lo = p * step;
      int hi = (lo + step < NN) ? lo + step : NN;
      fill_k<<<(EE / 4 + 255) / 256, 256, 0, stream>>>(ei, rend, colc, lo, hi);
    }
  }
  dinv_k<<<GR, 256, 0, stream>>>(rend, dinv, d2, sqd);

  // ---- layer 1: K=24, F=3 -> 32 ----
  sent_f3_k<<<1, 64, 0, stream>>>(Vf);
  prescale_x_k<<<GR, 256, 0, stream>>>(x, dinv, Vf);
  auto Vp = [&](int k) { return Vf + (size_t)k * (NN + 1); };
  cheb_f3_k<true><<<GR8, 256, 0, stream>>>(rend, colc, d2, Vp(0), nullptr, Vp(1));
  for (int k = 2; k < 24; ++k)
    cheb_f3_k<false><<<GR8, 256, 0, stream>>>(rend, colc, d2, Vp(k - 1), Vp(k - 2), Vp(k));
  gemm_l1_k<<<GR, 256, 0, stream>>>(x, Vf, W1, b1, dinv, sqd, Vh0, Vh1);

  // ---- layers 2/3: ring-6 half-pair planes + chunked SGPR GEMM ----
  sent_b16_k<<<1, 128, 0, stream>>>((uintT*)Vh0, (uintT*)Vh1, R);
  auto ringH = [&](int k, int h) {  // k >= 1
    return (uintT*)(R + (size_t)(((k - 1) % 6) * 2 + h) * HB);
  };
  auto run_layer = [&](const float* W, int K) {
    gemm_ch_k<1, true><<<GR, 256, 0, stream>>>((uintT*)Vh0, (uintT*)Vh1,
                                               nullptr, nullptr, W, acc);
    for (int k = 1; k < K; ++k) {
      for (int h = 0; h < 2; ++h) {
        const uintT* U = (k == 1) ? (h ? (uintT*)Vh1 : (uintT*)Vh0) : ringH(k - 1, h);
        if (k == 1)
          cheb_bh_k<true><<<GR8, 256, 0, stream>>>(rend, colc, d2, U, nullptr,
                                                   ringH(k, h));
        else {
          const uintT* Ap = (k == 2) ? (h ? (uintT*)Vh1 : (uintT*)Vh0) : ringH(k - 2, h);
          cheb_bh_k<false><<<GR8, 256, 0, stream>>>(rend, colc, d2, U, Ap,
                                                    ringH(k, h));
        }
      }
      if ((k & 1) == 0)  // chunk (k-1, k)
        gemm_ch_k<2, false><<<GR, 256, 0, stream>>>(
            ringH(k - 1, 0), ringH(k - 1, 1), ringH(k, 0), ringH(k, 1),
            W + (size_t)(k - 1) * 1024, acc);
    }
    if ((K - 1) & 1)  // odd tail plane
      gemm_ch_k<1, false><<<GR, 256, 0, stream>>>(
          ringH(K - 1, 0), ringH(K - 1, 1), nullptr, nullptr,
          W + (size_t)(K - 1) * 1024, acc);
  };
  run_layer(W2, 12);
  silu2_k<<<GE, 256, 0, stream>>>(acc, b2, sqd, dinv, Vh0, Vh1);
  run_layer(W3, 10);
  final2_k<<<GR, 256, 0, stream>>>(acc, b3, sqd, W4, out);
}

// Round 8
// 1869.817 us; speedup vs baseline: 1.1885x; 1.0321x over previous
//
#include <hip/hip_runtime.h>
#include <math.h>

#define NN 100000
#define EE 3200000
#define NCH 32
#define CAP 96          // padded CSR row capacity (deg~Poisson(32); P(>=96)~5e-20)
#define FILL_PASSES 8
#define HB 3200256      // aligned bytes per 16-channel bf16 half-table ((NN+1)*32 -> 256-pad)

typedef unsigned short ushortT;
typedef unsigned int uintT;

__device__ __forceinline__ ushortT f2b(float f) {
  uintT u = __float_as_uint(f);
  uintT r = u + 0x7fffu + ((u >> 16) & 1u);  // RNE
  return (ushortT)(r >> 16);
}
__device__ __forceinline__ uintT pack2(float x, float y) {
  return (uintT)f2b(x) | ((uintT)f2b(y) << 16);
}
__device__ __forceinline__ float lo2f(uintT u) { return __uint_as_float(u << 16); }
__device__ __forceinline__ float hi2f(uintT u) { return __uint_as_float(u & 0xffff0000u); }
__device__ __forceinline__ float silu(float v) { return v / (1.f + expf(-v)); }

// ---------------- setup ----------------

__global__ void init_cursor_k(int* __restrict__ cur) {
  int i = blockIdx.x * blockDim.x + threadIdx.x;
  if (i < NN) cur[i] = i * CAP;
}

// windowed scatter; col-vector loaded only when some lane-edge is in-window
__global__ void fill_k(const int* __restrict__ ei, int* __restrict__ cursor,
                       int* __restrict__ colc, int lo, int hi) {
  int t = blockIdx.x * blockDim.x + threadIdx.x;
  if (t * 4 >= EE) return;
  int4 r4 = ((const int4*)ei)[t];
  bool i0 = r4.x >= lo && r4.x < hi;
  bool i1 = r4.y >= lo && r4.y < hi;
  bool i2 = r4.z >= lo && r4.z < hi;
  bool i3 = r4.w >= lo && r4.w < hi;
  if (!(i0 | i1 | i2 | i3)) return;
  int4 c4 = ((const int4*)(ei + EE))[t];
  if (i0 && r4.x != c4.x) colc[atomicAdd(&cursor[r4.x], 1)] = c4.x;
  if (i1 && r4.y != c4.y) colc[atomicAdd(&cursor[r4.y], 1)] = c4.y;
  if (i2 && r4.z != c4.z) colc[atomicAdd(&cursor[r4.z], 1)] = c4.z;
  if (i3 && r4.w != c4.w) colc[atomicAdd(&cursor[r4.w], 1)] = c4.w;
}

__global__ void dinv_k(const int* __restrict__ rend, float* __restrict__ dinv,
                       float* __restrict__ d2, float* __restrict__ sqd) {
  int i = blockIdx.x * blockDim.x + threadIdx.x;
  if (i >= NN) return;
  int c = rend[i] - i * CAP;
  float di = (c > 0) ? rsqrtf((float)c) : 0.f;
  dinv[i] = di;
  d2[i] = di * di;
  sqd[i] = (c > 0) ? sqrtf((float)c) : 1.f;
}

// zero sentinel row NN of the 24 layer-1 bf16 planes (uint2 each)
__global__ void sent_f3_k(uint2* __restrict__ Vfb) {
  int t = threadIdx.x;
  if (t < 24) Vfb[(size_t)t * (NN + 1) + NN] = make_uint2(0u, 0u);
}

// zero sentinel rows of Vh halves + 12 ring half-tables (after layer 1)
__global__ void sent_b16_k(uintT* __restrict__ Vh0, uintT* __restrict__ Vh1,
                           char* __restrict__ R) {
  int t = threadIdx.x;  // 14 tables x 8 dwords = 112 threads
  int tb = t >> 3, d = t & 7;
  if (tb >= 14) return;
  uintT* base;
  if (tb == 12) base = Vh0;
  else if (tb == 13) base = Vh1;
  else base = (uintT*)(R + (size_t)tb * HB);
  base[(size_t)NN * 8 + d] = 0u;
}

// plane 0 = dinv * x, packed bf16 {(v0,v1),(v2,0)}
__global__ __launch_bounds__(256) void prescale_x_k(const float* __restrict__ x,
                                                    const float* __restrict__ dinv,
                                                    uint2* __restrict__ V0) {
  int i = blockIdx.x * blockDim.x + threadIdx.x;
  if (i >= NN) return;
  float di = dinv[i];
  V0[i] = make_uint2(pack2(di * x[3 * i], di * x[3 * i + 1]),
                     pack2(di * x[3 * i + 2], 0.f));
}

// ---------------- layer 1 ----------------

// 8 lanes/row, F=3, bf16 packed planes, V-space recurrence
template <bool FIRST>
__global__ __launch_bounds__(256) void cheb_f3_k(
    const int* __restrict__ rend, const int* __restrict__ colc,
    const float* __restrict__ d2, const uint2* __restrict__ U,
    const uint2* __restrict__ A, uint2* __restrict__ Vo) {
  int t8 = blockIdx.x * blockDim.x + threadIdx.x;
  int i = t8 >> 3, q = t8 & 7;
  if (i >= NN) return;
  int s = i * CAP, e = rend[i];
  float a0 = 0.f, a1 = 0.f, a2 = 0.f;
  for (int t = s + q; t < e; t += 32) {
#pragma unroll
    for (int u = 0; u < 4; ++u) {
      int tt = t + 8 * u;
      int cc = (tt < e) ? colc[tt] : NN;  // sentinel row NN is zero
      uint2 r = U[cc];
      a0 += lo2f(r.x); a1 += hi2f(r.x); a2 += lo2f(r.y);
    }
  }
  a0 += __shfl_xor(a0, 1); a1 += __shfl_xor(a1, 1); a2 += __shfl_xor(a2, 1);
  a0 += __shfl_xor(a0, 2); a1 += __shfl_xor(a1, 2); a2 += __shfl_xor(a2, 2);
  a0 += __shfl_xor(a0, 4); a1 += __shfl_xor(a1, 4); a2 += __shfl_xor(a2, 4);
  if (q == 0) {
    float d2i = d2[i];
    float v0, v1, v2;
    if (FIRST) {
      v0 = -d2i * a0; v1 = -d2i * a1; v2 = -d2i * a2;
    } else {
      uint2 ap = A[i];
      v0 = fmaf(-2.f * d2i, a0, -lo2f(ap.x));
      v1 = fmaf(-2.f * d2i, a1, -hi2f(ap.x));
      v2 = fmaf(-2.f * d2i, a2, -lo2f(ap.y));
    }
    Vo[i] = make_uint2(pack2(v0, v1), pack2(v2, 0.f));
  }
}

// compile-time plane-chunk partial: s_[32] += sum_{k=K0}^{K1-1} V_k . W1[k]
template <int K0, int K1>
__device__ __forceinline__ void sum_planes(const uint2* __restrict__ Vfb, int i,
                                           const float* __restrict__ W1,
                                           float* __restrict__ s_) {
#pragma unroll
  for (int k = K0; k < K1; ++k) {
    uint2 u = Vfb[(size_t)k * (NN + 1) + i];
    float v0 = lo2f(u.x), v1 = hi2f(u.x), v2 = lo2f(u.y);
    const float* Wk = W1 + k * 96;
#pragma unroll
    for (int j = 0; j < 32; ++j)
      s_[j] = fmaf(v0, Wk[j], fmaf(v1, Wk[32 + j], fmaf(v2, Wk[64 + j], s_[j])));
  }
}

// 4-wave k-split GEMM: block = 64 rows, wave w sums 6 planes (SGPR W),
// LDS-reduce (stride 36: conflict-benign), fused silu epilogue -> Vh halves.
__global__ __launch_bounds__(256) void gemm_l1_k(
    const float* __restrict__ x, const uint2* __restrict__ Vfb,
    const float* __restrict__ W1, const float* __restrict__ b1,
    const float* __restrict__ dinv, const float* __restrict__ sqd,
    ushortT* __restrict__ Vh0, ushortT* __restrict__ Vh1) {
  __shared__ float red[4 * 64 * 36];
  int tid = threadIdx.x;
  int w = tid >> 6, lane = tid & 63;
  int i = blockIdx.x * 64 + lane;
  float s_[32];
#pragma unroll
  for (int j = 0; j < 32; ++j) s_[j] = 0.f;
  if (i < NN) {
    if (w == 0) sum_planes<1, 7>(Vfb, i, W1, s_);
    else if (w == 1) sum_planes<7, 13>(Vfb, i, W1, s_);
    else if (w == 2) sum_planes<13, 19>(Vfb, i, W1, s_);
    else sum_planes<19, 24>(Vfb, i, W1, s_);
  }
  float* rb = &red[(w * 64 + lane) * 36];
#pragma unroll
  for (int j = 0; j < 32; ++j) rb[j] = s_[j];
  __syncthreads();
  // reduce: thread (r = tid>>2, q = tid&3) handles channels q*8..q*8+7
  int r = tid >> 2, q = tid & 3;
  int io = blockIdx.x * 64 + r;
  if (io >= NN) return;
  float acc8[8];
#pragma unroll
  for (int c = 0; c < 8; ++c) acc8[c] = 0.f;
#pragma unroll
  for (int ww = 0; ww < 4; ++ww) {
    const float* p = &red[(ww * 64 + r) * 36 + q * 8];
#pragma unroll
    for (int c = 0; c < 8; ++c) acc8[c] += p[c];
  }
  float x0 = x[3 * io], x1 = x[3 * io + 1], x2 = x[3 * io + 2];
  float sq = sqd[io], di = dinv[io];
  uintT o[4];
#pragma unroll
  for (int cp = 0; cp < 4; ++cp) {
    int j0 = q * 8 + 2 * cp, j1 = j0 + 1;
    float g0 = fmaf(sq, acc8[2 * cp],
        fmaf(x0, W1[j0], fmaf(x1, W1[32 + j0], fmaf(x2, W1[64 + j0], b1[j0]))));
    float g1 = fmaf(sq, acc8[2 * cp + 1],
        fmaf(x0, W1[j1], fmaf(x1, W1[32 + j1], fmaf(x2, W1[64 + j1], b1[j1]))));
    o[cp] = pack2(di * silu(g0), di * silu(g1));
  }
  uintT* dst = (uintT*)((q >> 1) ? Vh1 : Vh0) + (size_t)io * 8 + (q & 1) * 4;
  *(uint4*)dst = make_uint4(o[0], o[1], o[2], o[3]);
}

// ---------------- layers 2/3 ----------------

// Pure gather Chebyshev half-step. 8 lanes/row, lane g owns channel-pair g.
template <bool FIRST>
__global__ __launch_bounds__(256) void cheb_bh_k(
    const int* __restrict__ rend, const int* __restrict__ colc,
    const float* __restrict__ d2, const uintT* __restrict__ U,
    const uintT* __restrict__ Ap, uintT* __restrict__ Vo) {
  int t = blockIdx.x * blockDim.x + threadIdx.x;
  int i = t >> 3;
  if (i >= NN) return;
  int g = t & 7;
  int lb = (threadIdx.x & 63) & 56;  // 8-lane group base within wave
  int s = i * CAP, e = rend[i];
  float ax = 0.f, ay = 0.f;
  for (int b = s; b < e; b += 8) {
    int idx = b + g;
    int cl = (idx < e) ? colc[idx] : NN;  // sentinel -> zero row
#pragma unroll
    for (int u = 0; u < 8; ++u) {
      int cj = __shfl(cl, lb + u);
      uintT r = U[(size_t)cj * 8 + g];
      ax += lo2f(r); ay += hi2f(r);
    }
  }
  float d2i = d2[i];
  float vx, vy;
  if (FIRST) {
    vx = -d2i * ax; vy = -d2i * ay;
  } else {
    uintT au = Ap[(size_t)i * 8 + g];
    vx = fmaf(-2.f * d2i, ax, -lo2f(au));
    vy = fmaf(-2.f * d2i, ay, -hi2f(au));
  }
  Vo[(size_t)i * 8 + g] = pack2(vx, vy);
}

__device__ __forceinline__ void fma_pair(uintT dw, const float* __restrict__ Wc,
                                         float a[32]) {
  float vl = lo2f(dw), vh = hi2f(dw);
#pragma unroll
  for (int j = 0; j < 32; ++j) a[j] = fmaf(vl, Wc[j], a[j]);
#pragma unroll
  for (int j = 0; j < 32; ++j) a[j] = fmaf(vh, Wc[32 + j], a[j]);
}

__device__ __forceinline__ void plane_fma(const uintT* __restrict__ h0,
                                          const uintT* __restrict__ h1, size_t i,
                                          const float* __restrict__ W, float a[32]) {
  uint4 u0 = *(const uint4*)(h0 + i * 8);
  uint4 u1 = *(const uint4*)(h0 + i * 8 + 4);
  uint4 u2 = *(const uint4*)(h1 + i * 8);
  uint4 u3 = *(const uint4*)(h1 + i * 8 + 4);
  fma_pair(u0.x, W + 0 * 64, a);   fma_pair(u0.y, W + 1 * 64, a);
  fma_pair(u0.z, W + 2 * 64, a);   fma_pair(u0.w, W + 3 * 64, a);
  fma_pair(u1.x, W + 4 * 64, a);   fma_pair(u1.y, W + 5 * 64, a);
  fma_pair(u1.z, W + 6 * 64, a);   fma_pair(u1.w, W + 7 * 64, a);
  fma_pair(u2.x, W + 8 * 64, a);   fma_pair(u2.y, W + 9 * 64, a);
  fma_pair(u2.z, W + 10 * 64, a);  fma_pair(u2.w, W + 11 * 64, a);
  fma_pair(u3.x, W + 12 * 64, a);  fma_pair(u3.y, W + 13 * 64, a);
  fma_pair(u3.z, W + 14 * 64, a);  fma_pair(u3.w, W + 15 * 64, a);
}

// chunk GEMM: acc(+)= sum over NP planes of V_k @ W[k]. thread-per-row, SGPR W.
template <int NP, bool INIT>
__global__ __launch_bounds__(256) void gemm_ch_k(
    const uintT* __restrict__ A0, const uintT* __restrict__ A1,
    const uintT* __restrict__ B0, const uintT* __restrict__ B1,
    const float* __restrict__ W, float* __restrict__ acc) {
  int i = blockIdx.x * blockDim.x + threadIdx.x;
  if (i >= NN) return;
  float a[32];
  float4* ar = (float4*)(acc + (size_t)i * 32);
  if (INIT) {
#pragma unroll
    for (int j = 0; j < 32; ++j) a[j] = 0.f;
  } else {
#pragma unroll
    for (int q = 0; q < 8; ++q) {
      float4 v = ar[q];
      a[4 * q] = v.x; a[4 * q + 1] = v.y; a[4 * q + 2] = v.z; a[4 * q + 3] = v.w;
    }
  }
  plane_fma(A0, A1, (size_t)i, W, a);
  if (NP == 2) plane_fma(B0, B1, (size_t)i, W + 1024, a);
#pragma unroll
  for (int q = 0; q < 8; ++q)
    ar[q] = make_float4(a[4 * q], a[4 * q + 1], a[4 * q + 2], a[4 * q + 3]);
}

// layer transition: h = silu(sqd*acc + b); Vh = dinv*h
__global__ __launch_bounds__(256) void silu2_k(const float* __restrict__ acc,
                                               const float* __restrict__ b,
                                               const float* __restrict__ sqd,
                                               const float* __restrict__ dinv,
                                               ushortT* __restrict__ Vh0,
                                               ushortT* __restrict__ Vh1) {
  int t = blockIdx.x * blockDim.x + threadIdx.x;
  if (t >= NN * NCH) return;
  int i = t >> 5, j = t & 31;
  float g = fmaf(sqd[i], acc[t], b[j]);
  ushortT uv = f2b(dinv[i] * silu(g));
  if (j < 16) Vh0[(size_t)i * 16 + j] = uv;
  else        Vh1[(size_t)i * 16 + (j - 16)] = uv;
}

// final: out[i] = silu(sqd*acc + b3) . W4
__global__ __launch_bounds__(256) void final2_k(const float* __restrict__ acc,
                                                const float* __restrict__ b3,
                                                const float* __restrict__ sqd,
                                                const float* __restrict__ W4,
                                                float* __restrict__ out) {
  int i = blockIdx.x * blockDim.x + threadIdx.x;
  if (i >= NN) return;
  const float4* ar = (const float4*)(acc + (size_t)i * 32);
  float sq = sqd[i];
  float g = 0.f;
#pragma unroll
  for (int q = 0; q < 8; ++q) {
    float4 v = ar[q];
    g = fmaf(silu(fmaf(sq, v.x, b3[4 * q + 0])), W4[4 * q + 0], g);
    g = fmaf(silu(fmaf(sq, v.y, b3[4 * q + 1])), W4[4 * q + 1], g);
    g = fmaf(silu(fmaf(sq, v.z, b3[4 * q + 2])), W4[4 * q + 2], g);
    g = fmaf(silu(fmaf(sq, v.w, b3[4 * q + 3])), W4[4 * q + 3], g);
  }
  out[i] = g;
}

// ---------------- host ----------------

extern "C" void kernel_launch(void* const* d_in, const int* in_sizes, int n_in,
                              void* d_out, int out_size, void* d_ws, size_t ws_size,
                              hipStream_t stream) {
  const float* x = (const float*)d_in[0];
  const int* ei = (const int*)d_in[1];
  const float* W1 = (const float*)d_in[4];
  const float* b1 = (const float*)d_in[5];
  const float* W2 = (const float*)d_in[6];
  const float* b2 = (const float*)d_in[7];
  const float* W3 = (const float*)d_in[8];
  const float* b3 = (const float*)d_in[9];
  const float* W4 = (const float*)d_in[10];
  float* out = (float*)d_out;

  char* ws = (char*)d_ws;
  size_t off = 0;
  auto alloc = [&](size_t bytes) {
    void* p = ws + off;
    off += (bytes + 255) & ~(size_t)255;
    return p;
  };
  int* rend = (int*)alloc((size_t)NN * 4);
  float* dinv = (float*)alloc((size_t)NN * 4);
  float* d2 = (float*)alloc((size_t)NN * 4);
  float* sqd = (float*)alloc((size_t)NN * 4);
  int* colc = (int*)alloc((size_t)NN * CAP * 4);       // 38.4 MB padded CSR
  ushortT* Vh0 = (ushortT*)alloc(HB);                  // layer-input V halves
  ushortT* Vh1 = (ushortT*)alloc(HB);
  float* acc = (float*)alloc((size_t)NN * NCH * 4);    // 12.8 MB fp32 accumulator
  char* R = (char*)alloc((size_t)12 * HB);             // ring / layer-1 bf16 planes
  uint2* Vfb = (uint2*)R;                              // 24 x (NN+1) x 8B = 19.2 MB
  (void)ws_size; (void)in_sizes; (void)n_in; (void)out_size;

  const int GR = (NN + 255) / 256;        // thread-per-row grids
  const int GE = (NN * NCH + 255) / 256;  // element grids
  const int GR8 = (NN * 8 + 255) / 256;   // 8-lanes-per-row grids
  const int GL1 = (NN + 63) / 64;         // gemm_l1: 64 rows per block

  // ---- padded CSR build ----
  init_cursor_k<<<GR, 256, 0, stream>>>(rend);
  {
    int step = (NN + FILL_PASSES - 1) / FILL_PASSES;
    for (int p = 0; p < FILL_PASSES; ++p) {
      int lo = p * step;
      int hi = (lo + step < NN) ? lo + step : NN;
      fill_k<<<(EE / 4 + 255) / 256, 256, 0, stream>>>(ei, rend, colc, lo, hi);
    }
  }
  dinv_k<<<GR, 256, 0, stream>>>(rend, dinv, d2, sqd);

  // ---- layer 1: K=24, F=3 -> 32 (bf16 packed planes) ----
  sent_f3_k<<<1, 64, 0, stream>>>(Vfb);
  prescale_x_k<<<GR, 256, 0, stream>>>(x, dinv, Vfb);
  auto Vp = [&](int k) { return Vfb + (size_t)k * (NN + 1); };
  cheb_f3_k<true><<<GR8, 256, 0, stream>>>(rend, colc, d2, Vp(0), nullptr, Vp(1));
  for (int k = 2; k < 24; ++k)
    cheb_f3_k<false><<<GR8, 256, 0, stream>>>(rend, colc, d2, Vp(k - 1), Vp(k - 2), Vp(k));
  gemm_l1_k<<<GL1, 256, 0, stream>>>(x, Vfb, W1, b1, dinv, sqd, Vh0, Vh1);

  // ---- layers 2/3: ring-6 half-pair planes + chunked SGPR GEMM ----
  sent_b16_k<<<1, 128, 0, stream>>>((uintT*)Vh0, (uintT*)Vh1, R);
  auto ringH = [&](int k, int h) {  // k >= 1
    return (uintT*)(R + (size_t)(((k - 1) % 6) * 2 + h) * HB);
  };
  auto run_layer = [&](const float* W, int K) {
    gemm_ch_k<1, true><<<GR, 256, 0, stream>>>((uintT*)Vh0, (uintT*)Vh1,
                                               nullptr, nullptr, W, acc);
    for (int k = 1; k < K; ++k) {
      for (int h = 0; h < 2; ++h) {
        const uintT* U = (k == 1) ? (h ? (uintT*)Vh1 : (uintT*)Vh0) : ringH(k - 1, h);
        if (k == 1)
          cheb_bh_k<true><<<GR8, 256, 0, stream>>>(rend, colc, d2, U, nullptr,
                                                   ringH(k, h));
        else {
          const uintT* Ap = (k == 2) ? (h ? (uintT*)Vh1 : (uintT*)Vh0) : ringH(k - 2, h);
          cheb_bh_k<false><<<GR8, 256, 0, stream>>>(rend, colc, d2, U, Ap,
                                                    ringH(k, h));
        }
      }
      if ((k & 1) == 0)  // chunk (k-1, k)
        gemm_ch_k<2, false><<<GR, 256, 0, stream>>>(
            ringH(k - 1, 0), ringH(k - 1, 1), ringH(k, 0), ringH(k, 1),
            W + (size_t)(k - 1) * 1024, acc);
    }
    if ((K - 1) & 1)  // odd tail plane
      gemm_ch_k<1, false><<<GR, 256, 0, stream>>>(
          ringH(K - 1, 0), ringH(K - 1, 1), nullptr, nullptr,
          W + (size_t)(K - 1) * 1024, acc);
  };
  run_layer(W2, 12);
  silu2_k<<<GE, 256, 0, stream>>>(acc, b2, sqd, dinv, Vh0, Vh1);
  run_layer(W3, 10);
  final2_k<<<GR, 256, 0, stream>>>(acc, b3, sqd, W4, out);
}